// Round 9
// baseline (712.453 us; speedup 1.0000x reference)
//
#include <hip/hip_runtime.h>
#include <hip/hip_bf16.h>
#include <stdint.h>

typedef unsigned short u16;
typedef __attribute__((ext_vector_type(8))) short short8;
typedef __attribute__((ext_vector_type(4))) float floatx4;

#define B_   512
#define D_   512
#define C_   100000

#define SCALE_  64.0f
#define COSM_   0.8775825618903728f
#define SINM_   0.479425538604203f
#define TH_     (-0.8775825618903728f)
#define MM_     0.2397127693021015f
#define EPS_    1e-7f
#define SHIFT_  89.6f

#define BM 256
#define BN 64
#define BK 32
#define NTILES 1563          // ceil(100000/64)
#define CHUNK  4             // c-tiles per block
#define NCH    391           // ceil(1563/4)
#define PADP   392           // partial row stride (floats)

__device__ inline float wave_reduce_sum(float v) {
    v += __shfl_xor(v, 1);
    v += __shfl_xor(v, 2);
    v += __shfl_xor(v, 4);
    v += __shfl_xor(v, 8);
    v += __shfl_xor(v, 16);
    v += __shfl_xor(v, 32);
    return v;
}

__device__ inline u16 f2bf(float x) {
    union { float f; uint32_t u; } v; v.f = x;
    uint32_t r = v.u + 0x7fffu + ((v.u >> 16) & 1u);  // RNE
    return (u16)(r >> 16);
}

// RNE pack of two fp32 -> one dword of 2x bf16 (v_cvt_pk_bf16_f32)
__device__ inline uint32_t cvt2_rn(float a, float b) {
    union { __hip_bfloat162 h; uint32_t u; } v;
    v.h = __float22bfloat162_rn(make_float2(a, b));
    return v.u;
}

// Fused: normalize embedding rows -> e_bf16, per-row phi (exact fp32 path),
// and zero-init rowsum (needed only for the atomic fallback path).
__global__ __launch_bounds__(256) void norm_e_phi_kernel(
    const float* __restrict__ emb, const float* __restrict__ w_raw,
    const int* __restrict__ gt, u16* __restrict__ e_bf16,
    float* __restrict__ phi, float* __restrict__ rowsum) {
    if (threadIdx.x < 4) rowsum[blockIdx.x * 4 + threadIdx.x] = 0.0f;
    int wv = threadIdx.x >> 6;
    int lane = threadIdx.x & 63;
    int b = blockIdx.x * 4 + wv;
    const float4* rp = (const float4*)(emb + (long)b * D_);
    float4 f0 = rp[lane], f1 = rp[lane + 64];
    float sq = f0.x*f0.x + f0.y*f0.y + f0.z*f0.z + f0.w*f0.w
             + f1.x*f1.x + f1.y*f1.y + f1.z*f1.z + f1.w*f1.w;
    sq = wave_reduce_sum(sq);
    float rn = 1.0f / sqrtf(sq);
    f0.x *= rn; f0.y *= rn; f0.z *= rn; f0.w *= rn;
    f1.x *= rn; f1.y *= rn; f1.z *= rn; f1.w *= rn;
    uint2 p0, p1;
    p0.x = (uint32_t)f2bf(f0.x) | ((uint32_t)f2bf(f0.y) << 16);
    p0.y = (uint32_t)f2bf(f0.z) | ((uint32_t)f2bf(f0.w) << 16);
    p1.x = (uint32_t)f2bf(f1.x) | ((uint32_t)f2bf(f1.y) << 16);
    p1.y = (uint32_t)f2bf(f1.z) | ((uint32_t)f2bf(f1.w) << 16);
    uint2* ob = (uint2*)(e_bf16 + (long)b * D_);
    ob[lane] = p0;
    ob[lane + 64] = p1;

    int g = gt[b];
    const float4* wp = (const float4*)(w_raw + (long)g * D_);
    float4 w0 = wp[lane], w1 = wp[lane + 64];
    float dt = f0.x*w0.x + f0.y*w0.y + f0.z*w0.z + f0.w*w0.w
             + f1.x*w1.x + f1.y*w1.y + f1.z*w1.z + f1.w*w1.w;
    float wsq = w0.x*w0.x + w0.y*w0.y + w0.z*w0.z + w0.w*w0.w
              + w1.x*w1.x + w1.y*w1.y + w1.z*w1.z + w1.w*w1.w;
    dt = wave_reduce_sum(dt);
    wsq = wave_reduce_sum(wsq);
    if (lane == 0) {
        float pos = dt / sqrtf(wsq);
        pos = fminf(fmaxf(pos, -1.0f + EPS_), 1.0f - EPS_);
        float s2 = 1.0f - pos * pos;
        s2 = fminf(fmaxf(s2, EPS_), 1.0f - EPS_);
        float sin_t = sqrtf(s2);
        float ph = pos * COSM_ - sin_t * SINM_;
        ph = (pos > TH_) ? ph : (pos - MM_);
        phi[b] = ph;
    }
}

__device__ inline void cvt_store(const float4& v0, const float4& v1,
                                 u16* dst, float& sq) {
    uint4 q;
    q.x = cvt2_rn(v0.x, v0.y);
    q.y = cvt2_rn(v0.z, v0.w);
    q.z = cvt2_rn(v1.x, v1.y);
    q.w = cvt2_rn(v1.z, v1.w);
    *(uint4*)dst = q;
    sq += v0.x*v0.x + v0.y*v0.y + v0.z*v0.z + v0.w*v0.w
        + v1.x*v1.x + v1.y*v1.y + v1.z*v1.z + v1.w*v1.w;
}

// GEMM + ArcFace + exp row-sums. K-loop body identical to the proven 242us
// r6 kernel. Structural change: NO contended atomics. Diagnosis (r8): the
// session-long ~245us plateau was epilogue atomicAdd contention -- 800K+
// device-scope RMWs onto a 2KB rowsum array ping-ponging ~32 cache lines
// across 8 non-coherent XCDs (r8: 2x atomics -> WRITE_SIZE 12.5->150MB,
// FETCH +60MB, time 242->378us), serializing in the TCC and backpressuring
// all loads. Now each block covers CHUNK=4 c-tiles (grid 782 = one
// residency pass), accumulates exp-sums in registers across the chunk, and
// writes ONE uncontended float per (row,chunk) to a partial buffer; a tiny
// reduce kernel folds partials. Fallback to (4x fewer) atomics if the
// workspace is too small for partials.
__global__ __launch_bounds__(256, 3) void gemm_arcface_fused(
    const u16* __restrict__ a_g,     // e_bf16 [512][512]
    const float* __restrict__ w_g,   // raw weight fp32 [100000][512]
    const float* __restrict__ phi, const int* __restrict__ gt,
    float* __restrict__ rowsum, float* __restrict__ partial) {
    __shared__ __align__(16) u16 b_tile[2][BN * BK];  // 2 x 4 KB
    __shared__ float phi_s[BM];
    __shared__ int gt_s[BM];
    __shared__ float rnorm_s[BN];

    int tid = threadIdx.x;
    int chunk = blockIdx.x >> 1;
    int m0 = (blockIdx.x & 1) * BM;
    int nt = min(CHUNK, NTILES - chunk * CHUNK);

    phi_s[tid] = phi[m0 + tid];
    gt_s[tid] = gt[m0 + tid];

    // staging geometry (r0 scheme, measured 0 bank conflicts)
    int rb = tid >> 2;
    int bslot = tid & 3;
    int bkq = bslot ^ ((rb >> 1) & 3);
    u16* b_dst0 = &b_tile[0][rb * BK + bslot * 8];
    u16* b_dst1 = &b_tile[1][rb * BK + bslot * 8];

    int wv = tid >> 6, lane = tid & 63;
    int low4 = lane & 15, quad = lane >> 4;
    int lslot = quad ^ ((low4 >> 1) & 3);
    const u16* a_base = a_g + (long)(m0 + wv * 64 + low4) * D_ + quad * 8;
    int bf_off = low4 * BK + lslot * 8;

    float rs[4][4] = {{0.0f}};   // per-(mi,r) running exp-sums across chunk

#pragma unroll 1
    for (int ct = 0; ct < nt; ct++) {
        int c0 = (chunk * CHUNK + ct) * BN;
        long brow_g = min(c0 + rb, C_ - 1);
        const float4* b_src = (const float4*)(w_g + brow_g * (long)D_ + bkq * 8);

        floatx4 acc[4][4] = {};
        float sq = 0.0f;
        float4 bv[4][2];     // 4-deep B register pipeline
        short8 afc[4];

        // prologue: tiles 0..3 in flight; tile 0 converted into LDS buf 0
#pragma unroll
        for (int j = 0; j < 4; j++) {
            bv[j][0] = b_src[j * 8];
            bv[j][1] = b_src[j * 8 + 1];
        }
        cvt_store(bv[0][0], bv[0][1], b_dst0, sq);
        asm volatile("s_waitcnt lgkmcnt(0)" ::: "memory");
        __builtin_amdgcn_s_barrier();

#pragma unroll
        for (int kt = 0; kt < 16; kt++) {
            int p = kt & 1;
            if (kt < 12) {   // issue tile kt+4 into the freed slot
                bv[kt & 3][0] = b_src[(kt + 4) * 8];
                bv[kt & 3][1] = b_src[(kt + 4) * 8 + 1];
            }
#pragma unroll
            for (int mi = 0; mi < 4; mi++)
                afc[mi] = *(const short8*)(a_base + (long)mi * 16 * D_ + kt * BK);
            short8 bf[4];
#pragma unroll
            for (int ni = 0; ni < 4; ni++)
                bf[ni] = *(const short8*)(&b_tile[p][ni * 16 * BK + bf_off]);
#pragma unroll
            for (int mi = 0; mi < 4; mi++)
#pragma unroll
                for (int ni = 0; ni < 4; ni++)
                    acc[mi][ni] = __builtin_amdgcn_mfma_f32_16x16x32_bf16(
                        afc[mi], bf[ni], acc[mi][ni], 0, 0, 0);
            if (kt < 15)
                cvt_store(bv[(kt + 1) & 3][0], bv[(kt + 1) & 3][1],
                          p ? b_dst0 : b_dst1, sq);
            asm volatile("s_waitcnt lgkmcnt(0)" ::: "memory");
            __builtin_amdgcn_s_barrier();
        }

        // per-column 1/||w||: 4 staging threads of a row hold disjoint slices
        sq += __shfl_xor(sq, 1);
        sq += __shfl_xor(sq, 2);
        if ((tid & 3) == 0) rnorm_s[rb] = 1.0f / sqrtf(sq);
        __syncthreads();

        // epilogue: normalize, clip, reweight, gt-substitute, exp -> rs
#pragma unroll
        for (int mi = 0; mi < 4; mi++) {
#pragma unroll
            for (int r = 0; r < 4; r++) {
                int rl = wv * 64 + mi * 16 + quad * 4 + r;
                float ph = phi_s[rl];
                int g = gt_s[rl];
                float s = 0.0f;
#pragma unroll
                for (int ni = 0; ni < 4; ni++) {
                    int cl = ni * 16 + low4;
                    int c = c0 + cl;
                    float v = acc[mi][ni][r] * rnorm_s[cl];
                    v = fminf(fmaxf(v, -1.0f + EPS_), 1.0f - EPS_);
                    float logit = (v > ph) ? (1.2f * v + 0.2f) : v;
                    logit *= SCALE_;
                    if (c == g) logit = SCALE_ * ph;
                    s += (c < C_) ? __expf(logit - SHIFT_) : 0.0f;
                }
                s += __shfl_xor(s, 1);
                s += __shfl_xor(s, 2);
                s += __shfl_xor(s, 4);
                s += __shfl_xor(s, 8);
                rs[mi][r] += s;
            }
        }
    }

    // one write per (row, chunk) -- zero contention
    if (partial) {
        if (low4 == 0) {
#pragma unroll
            for (int mi = 0; mi < 4; mi++)
#pragma unroll
                for (int r = 0; r < 4; r++) {
                    int rl = wv * 64 + mi * 16 + quad * 4 + r;
                    partial[(long)(m0 + rl) * PADP + chunk] = rs[mi][r];
                }
        }
    } else {
        if (low4 == 0) {
#pragma unroll
            for (int mi = 0; mi < 4; mi++)
#pragma unroll
                for (int r = 0; r < 4; r++) {
                    int rl = wv * 64 + mi * 16 + quad * 4 + r;
                    atomicAdd(&rowsum[m0 + rl], rs[mi][r]);
                }
        }
    }
}

// fold partials: rowsum[b] = sum_p partial[b][p]
__global__ __launch_bounds__(256) void reduce_rowsum_kernel(
    const float* __restrict__ partial, float* __restrict__ rowsum) {
    int wv = threadIdx.x >> 6, lane = threadIdx.x & 63;
    int b = blockIdx.x * 4 + wv;
    const float* p = partial + (long)b * PADP;
    float s = 0.0f;
    for (int i = lane; i < NCH; i += 64) s += p[i];
    s = wave_reduce_sum(s);
    if (lane == 0) rowsum[b] = s;
}

__global__ __launch_bounds__(256) void loss_kernel(
    const float* __restrict__ rowsum, const float* __restrict__ phi,
    float* __restrict__ out) {
    __shared__ float red[4];
    int tid = threadIdx.x;
    float s = 0.0f;
    for (int b = tid; b < B_; b += 256)
        s += logf(rowsum[b]) + SHIFT_ - SCALE_ * phi[b];
    s = wave_reduce_sum(s);
    int wv = tid >> 6, lane = tid & 63;
    if (lane == 0) red[wv] = s;
    __syncthreads();
    if (tid == 0) out[0] = (red[0] + red[1] + red[2] + red[3]) * (1.0f / B_);
}

extern "C" void kernel_launch(void* const* d_in, const int* in_sizes, int n_in,
                              void* d_out, int out_size, void* d_ws, size_t ws_size,
                              hipStream_t stream) {
    const float* emb = (const float*)d_in[0];   // [512][512] f32
    const float* wgt = (const float*)d_in[1];   // [100000][512] f32
    const int* gt = (const int*)d_in[2];        // [512] int32
    float* out = (float*)d_out;

    char* ws = (char*)d_ws;
    u16* e_bf16 = (u16*)(ws);                   //   524,288 B
    float* phi = (float*)(ws + 524288);         //     2,048 B
    float* rowsum = (float*)(ws + 526336);      //     2,048 B
    size_t need = 528384 + (size_t)B_ * PADP * 4;   // + 802,816 B partials
    float* partial = (ws_size >= need) ? (float*)(ws + 528384) : nullptr;

    norm_e_phi_kernel<<<B_ / 4, 256, 0, stream>>>(emb, wgt, gt, e_bf16, phi, rowsum);
    gemm_arcface_fused<<<NCH * 2, 256, 0, stream>>>(e_bf16, wgt, phi, gt, rowsum, partial);
    if (partial)
        reduce_rowsum_kernel<<<B_ / 4, 256, 0, stream>>>(partial, rowsum);
    loss_kernel<<<1, 256, 0, stream>>>(rowsum, phi, out);
}